// Round 1
// baseline (160.403 us; speedup 1.0000x reference)
//
#include <hip/hip_runtime.h>
#include <math.h>

#define HH 512
#define WW 512
#define TILE 64
#define HALO 2
#define LW (TILE + 2 * HALO)   // 68

// Summed kernels (precomputed from F1..F8 on paper):
// K1 = K3 = [[0,0,0,0,0],[0,1,1,1,0],[0,1,-8,1,0],[0,1,1,1,0],[0,0,0,0,0]]   (div 8 w=1; div 4 w=1)
// K2 = [[0,0,-1,0,0],[0,3,6,3,0],[-1,6,-24,6,-1],[0,3,6,3,0],[0,0,-1,0,0]]   (div 8 w=1)
// K4 = [[0,0,0,0,0],[0,-2,6,-2,0],[0,6,-16,6,0],[0,-2,6,-2,0],[0,0,0,0,0]]   (div 4 w=1)
// K6 = [[2,4,-6,4,2],[4,-12,24,-12,4],[-6,24,-48,24,-6],[4,-12,24,-12,4],[2,4,-6,4,2]] (div 4 w=2)
// K8 = [[-1,2,-2,2,-1],[2,-6,8,-6,2],[-2,8,-12,8,-2],[2,-6,8,-6,2],[-1,2,-2,2,-1]]    (no div, w=1)
// All are symmetric in x and y -> evaluate via g_{j,i} = (vertical +/-j sum) of h_i,
// where h0 = s[x], h1 = s[x-1]+s[x+1], h2 = s[x-2]+s[x+2].

__global__ __launch_bounds__(256, 8) void highpass_kernel(
    const float* __restrict__ src, float* __restrict__ out, int nb)
{
    __shared__ float smem[LW * LW];

    const int tid = threadIdx.x;
    const int x0 = blockIdx.x * TILE;
    const int y0 = blockIdx.y * TILE;
    const int b  = blockIdx.z;

    const float* __restrict__ c0 = src + (size_t)b * 3 * HH * WW;
    const float* __restrict__ c1 = c0 + HH * WW;
    const float* __restrict__ c2 = c0 + 2 * HH * WW;

    // Load s = c0+c1+c2 with reflect-2 padding into LDS.
    for (int idx = tid; idx < LW * LW; idx += 256) {
        int i = idx / LW;
        int j = idx - i * LW;
        int gy = y0 - HALO + i;
        int gx = x0 - HALO + j;
        gy = gy < 0 ? -gy : gy;
        gy = gy >= HH ? 2 * HH - 2 - gy : gy;
        gx = gx < 0 ? -gx : gx;
        gx = gx >= WW ? 2 * WW - 2 - gx : gx;
        int g = gy * WW + gx;
        smem[idx] = c0[g] + c1[g] + c2[g];
    }
    __syncthreads();

    const int tx = tid & 63;   // x within tile (wave = one row of 64 -> conflict-free LDS)
    const int ty = tid >> 6;   // 0..3
    const int yb = ty * 16;    // this thread's output rows: yb..yb+15

    const float GRAY  = (float)(0.2989 + 0.587 + 0.114);
    const float SCALE = GRAY / 7.0f;

    float h0[5], h1[5], h2[5];

    // Preload ring slots for s-rows yb+0 .. yb+3 (slot = k % 5, compile-time).
#pragma unroll
    for (int k = 0; k < 4; ++k) {
        const float* row = &smem[(yb + k) * LW + tx];
        float a = row[0], bb = row[1], c = row[2], d = row[3], e = row[4];
        h0[k] = c;
        h1[k] = bb + d;
        h2[k] = a + e;
    }

    size_t obase = (size_t)b * HH * WW + (size_t)(y0 + yb) * WW + (size_t)(x0 + tx);

#pragma unroll
    for (int oy = 0; oy < 16; ++oy) {
        {   // slide: load s-row yb+oy+4 into ring
            const int k = oy + 4;
            const float* row = &smem[(yb + k) * LW + tx];
            float a = row[0], bb = row[1], c = row[2], d = row[3], e = row[4];
            const int sl = k % 5;
            h0[sl] = c;
            h1[sl] = bb + d;
            h2[sl] = a + e;
        }
        const int sc  = (oy + 2) % 5;
        const int sm1 = (oy + 1) % 5, sp1 = (oy + 3) % 5;
        const int sm2 = (oy + 0) % 5, sp2 = (oy + 4) % 5;

        const float g00 = h0[sc],  g01 = h1[sc],  g02 = h2[sc];
        const float g10 = h0[sm1] + h0[sp1];
        const float g11 = h1[sm1] + h1[sp1];
        const float g12 = h2[sm1] + h2[sp1];
        const float g20 = h0[sm2] + h0[sp2];
        const float g21 = h1[sm2] + h1[sp2];
        const float g22 = h2[sm2] + h2[sp2];

        const float C1 = -8.f * g00 + g01 + g10 + g11;
        const float C2 = -24.f * g00 + 6.f * g01 - g02 + 6.f * g10 + 3.f * g11 - g20;
        const float C4 = -16.f * g00 + 6.f * g01 + 6.f * g10 - 2.f * g11;
        const float C6 = -48.f * g00 + 24.f * g01 - 6.f * g02
                       +  24.f * g10 - 12.f * g11 + 4.f * g12
                       -   6.f * g20 +  4.f * g21 + 2.f * g22;
        const float C8 = -12.f * g00 + 8.f * g01 - 2.f * g02
                       +   8.f * g10 - 6.f * g11 + 2.f * g12
                       -   2.f * g20 + 2.f * g21 - g22;

        const float v = floorf(C1 * 0.125f) + floorf(C2 * 0.125f)
                      + floorf(C1 * 0.25f)  + floorf(C4 * 0.25f)
                      + 2.f * floorf(C6 * 0.25f) + C8;

        out[obase + (size_t)oy * WW] = v * SCALE;
    }
    (void)nb;
}

extern "C" void kernel_launch(void* const* d_in, const int* in_sizes, int n_in,
                              void* d_out, int out_size, void* d_ws, size_t ws_size,
                              hipStream_t stream) {
    const float* src = (const float*)d_in[0];
    float* out = (float*)d_out;
    const int nb = in_sizes[0] / (3 * HH * WW);   // 32
    dim3 grid(WW / TILE, HH / TILE, nb);          // 8 x 8 x 32 = 2048 blocks
    highpass_kernel<<<grid, 256, 0, stream>>>(src, out, nb);
}